// Round 1
// baseline (2250.293 us; speedup 1.0000x reference)
//
#include <hip/hip_runtime.h>
#include <hip/hip_bf16.h>

#define NT   21
#define SEQ  1024
#define DIM  3072
#define NH   24
#define HD   128
#define ENCD 768
#define NAK  32
#define LTOT (NT*SEQ)    /* 21504 */
#define MKV  (NT*NAK)    /* 672   */

typedef __bf16 bf16x8 __attribute__((ext_vector_type(8)));
typedef float  f32x4  __attribute__((ext_vector_type(4)));

__device__ __forceinline__ ushort f2bf_rne(float f) {
    unsigned int u = __float_as_uint(f);
    u += 0x7FFFu + ((u >> 16) & 1u);
    return (ushort)(u >> 16);
}

// ---------------------------------------------------------------- conversions
__global__ void cvt_kernel(const float* __restrict__ src, ushort* __restrict__ dst, int n4) {
    int i = blockIdx.x * blockDim.x + threadIdx.x;
    int stride = gridDim.x * blockDim.x;
    for (; i < n4; i += stride) {
        float4 v = ((const float4*)src)[i];
        ushort4 o;
        o.x = f2bf_rne(v.x); o.y = f2bf_rne(v.y);
        o.z = f2bf_rne(v.z); o.w = f2bf_rne(v.w);
        ((ushort4*)dst)[i] = o;
    }
}

// ---------------------------------------------------------------- min/max of the two attn-map rows
__global__ void minmax_kernel(const float* __restrict__ m, float* __restrict__ mm) {
    __shared__ float red[4][256];
    int tid = threadIdx.x;
    float mn0 = 3.4e38f, mx0 = -3.4e38f, mn1 = 3.4e38f, mx1 = -3.4e38f;
    for (int i = tid; i < LTOT; i += 256) {
        float a = m[i], b = m[LTOT + i];
        mn0 = fminf(mn0, a); mx0 = fmaxf(mx0, a);
        mn1 = fminf(mn1, b); mx1 = fmaxf(mx1, b);
    }
    red[0][tid] = mn0; red[1][tid] = mx0; red[2][tid] = mn1; red[3][tid] = mx1;
    __syncthreads();
    for (int s = 128; s > 0; s >>= 1) {
        if (tid < s) {
            red[0][tid] = fminf(red[0][tid], red[0][tid + s]);
            red[1][tid] = fmaxf(red[1][tid], red[1][tid + s]);
            red[2][tid] = fminf(red[2][tid], red[2][tid + s]);
            red[3][tid] = fmaxf(red[3][tid], red[3][tid + s]);
        }
        __syncthreads();
    }
    if (tid == 0) { mm[0]=red[0][0]; mm[1]=red[1][0]; mm[2]=red[2][0]; mm[3]=red[3][0]; }
}

__global__ void pos_kernel(const float* __restrict__ m, const float* __restrict__ mm,
                           float* __restrict__ pos) {
    int i = blockIdx.x * 256 + threadIdx.x;
    if (i >= LTOT) return;
    float a = m[i], b = m[LTOT + i];
    float h1 = (a - mm[0]) * (4.0f / (mm[1] - mm[0]));               // [0,4]
    float h2 = (b - mm[2]) * (4.0f / (mm[3] - mm[2])) + 20.0f;       // [20,24]
    pos[i] = (a >= b) ? h1 : h2;   // argmax over 2 rows; 'back' row is unreachable
}

// ---------------------------------------------------------------- fused bf16 GEMM (+LN+RoPE epilogues)
// MODE 0: q = x@q_w^T + q_b -> LN(1e-6,qn) -> RoPE(pos[leff]) -> q[b,h,s,d] (in d_out)
// MODE 1: kv = enc@kv_w^T + kv_b; cols<3072: k -> LN(1e-5,kn) -> RoPE(2/22) -> k_ws ; else v -> v_ws
// MODE 2: out = o@proj_w^T + proj_b -> d_out row-major
struct __align__(16) GemmSmem {
    union {
        ushort stage[2 * 128 * 32];  // A tile then B tile (8KB + 8KB)
        float  epi[64 * 133];        // half-tile epilogue buffer (34,048 B)
    };
};

template <int MODE>
__global__ __launch_bounds__(256, 2) void gemm_bf16_kernel(
    const ushort* __restrict__ A, const ushort* __restrict__ W,
    const float* __restrict__ bias,
    const float* __restrict__ lng, const float* __restrict__ lnb,
    const float* __restrict__ pos,
    float* __restrict__ out0, float* __restrict__ kws, float* __restrict__ vws,
    int M, int K)
{
    __shared__ GemmSmem sh;
    const int tid  = threadIdx.x;
    const int lane = tid & 63;
    const int wave = tid >> 6;
    const int wm = wave >> 1, wn = wave & 1;
    const int m0 = blockIdx.y * 128;
    const int n0 = blockIdx.x * 128;
    const int quad = lane >> 4, r16 = lane & 15;

    char* smA = (char*)sh.stage;
    char* smB = smA + 8192;

    f32x4 acc[4][4] = {};

    const int nK = K >> 5;
    for (int kt = 0; kt < nK; ++kt) {
        const int k0 = kt << 5;
        __syncthreads();
        // ---- stage A tile (128 rows x 32 bf16), 16B chunks, XOR-swizzled slots
        #pragma unroll
        for (int j = 0; j < 2; ++j) {
            int ci = (wave * 2 + j) * 64 + lane;          // LDS slot index
            int r  = ci >> 2;
            int c  = (ci & 3) ^ ((r >> 1) & 3);           // global chunk for this slot
            int row = m0 + r; if (row > M - 1) row = M - 1;
            const ushort* gp = A + (size_t)row * K + (k0 + c * 8);
            __builtin_amdgcn_global_load_lds(
                (const __attribute__((address_space(1))) void*)gp,
                (__attribute__((address_space(3))) void*)(smA + (wave * 2 + j) * 1024),
                16, 0, 0);
        }
        // ---- stage B tile (weights rows n0..n0+127)
        #pragma unroll
        for (int j = 0; j < 2; ++j) {
            int ci = (wave * 2 + j) * 64 + lane;
            int r  = ci >> 2;
            int c  = (ci & 3) ^ ((r >> 1) & 3);
            const ushort* gp = W + (size_t)(n0 + r) * K + (k0 + c * 8);
            __builtin_amdgcn_global_load_lds(
                (const __attribute__((address_space(1))) void*)gp,
                (__attribute__((address_space(3))) void*)(smB + (wave * 2 + j) * 1024),
                16, 0, 0);
        }
        __syncthreads();  // compiler drains vmcnt(0) before s_barrier

        bf16x8 af[4], bfr[4];
        #pragma unroll
        for (int t = 0; t < 4; ++t) {
            int ra = wm * 64 + t * 16 + r16;
            af[t] = *(const bf16x8*)(smA + ra * 64 + ((quad ^ ((ra >> 1) & 3)) << 4));
            int rb = wn * 64 + t * 16 + r16;
            bfr[t] = *(const bf16x8*)(smB + rb * 64 + ((quad ^ ((rb >> 1) & 3)) << 4));
        }
        #pragma unroll
        for (int t = 0; t < 4; ++t)
            #pragma unroll
            for (int u = 0; u < 4; ++u)
                acc[t][u] = __builtin_amdgcn_mfma_f32_16x16x32_bf16(af[t], bfr[u], acc[t][u], 0, 0, 0);
    }

    // ---------------- epilogue: two 64-row phases through LDS
    const float inv128 = 1.0f / 128.0f;
    #pragma unroll
    for (int ph = 0; ph < 2; ++ph) {
        __syncthreads();
        if (wm == ph) {
            #pragma unroll
            for (int t = 0; t < 4; ++t)
                #pragma unroll
                for (int u = 0; u < 4; ++u)
                    #pragma unroll
                    for (int r = 0; r < 4; ++r) {
                        int ml = t * 16 + quad * 4 + r;        // 0..63 (within phase band)
                        int nl = wn * 64 + u * 16 + r16;       // 0..127
                        sh.epi[ml * 133 + nl] = acc[t][u][r];
                    }
        }
        __syncthreads();
        if (tid < 64) {
            int gm = m0 + ph * 64 + tid;
            if (gm < M) {
                float* rowp = &sh.epi[tid * 133];
                if (MODE == 2) {
                    float* op = out0 + (size_t)gm * DIM + n0;
                    #pragma unroll 8
                    for (int j = 0; j < 128; j += 4) {
                        float4 b4 = *(const float4*)(bias + n0 + j);
                        float4 v;
                        v.x = rowp[j]     + b4.x;
                        v.y = rowp[j + 1] + b4.y;
                        v.z = rowp[j + 2] + b4.z;
                        v.w = rowp[j + 3] + b4.w;
                        *(float4*)(op + j) = v;
                    }
                } else {
                    bool do_ln; float eps = 0.f, pv = 0.f; float* op;
                    if (MODE == 0) {
                        do_ln = true; eps = 1e-6f;
                        int head = n0 >> 7;
                        int b = gm >> 10, s = gm & 1023;
                        int leff = ((b * NH + head) * SEQ + s) % LTOT;   // bug-faithful flat reshape
                        pv = pos[leff];
                        op = out0 + ((size_t)(b * NH + head) * SEQ + s) * HD;
                    } else {                // MODE 1
                        int b = gm / NAK, n = gm - b * NAK;
                        if (n0 < DIM) {     // k path
                            do_ln = true; eps = 1e-5f;
                            int head = n0 >> 7;
                            pv = (n < 16) ? 2.0f : 22.0f;
                            op = kws + ((size_t)(b * NH + head) * NAK + n) * HD;
                        } else {            // v path: bias only
                            do_ln = false;
                            int head = (n0 - DIM) >> 7;
                            op = vws + ((size_t)(b * NH + head) * NAK + n) * HD;
                        }
                    }
                    if (!do_ln) {
                        #pragma unroll 8
                        for (int j = 0; j < 128; j += 4) {
                            float4 b4 = *(const float4*)(bias + n0 + j);
                            float4 v;
                            v.x = rowp[j]     + b4.x;
                            v.y = rowp[j + 1] + b4.y;
                            v.z = rowp[j + 2] + b4.z;
                            v.w = rowp[j + 3] + b4.w;
                            *(float4*)(op + j) = v;
                        }
                    } else {
                        float s1 = 0.f, s2 = 0.f;
                        #pragma unroll 8
                        for (int j = 0; j < 128; ++j) {
                            float val = rowp[j] + bias[n0 + j];
                            rowp[j] = val;
                            s1 += val; s2 += val * val;
                        }
                        float mean = s1 * inv128;
                        float var  = s2 * inv128 - mean * mean;
                        float rinv = rsqrtf(var + eps);
                        // LN + interleaved RoPE, pairs (2i, 2i+1)
                        #pragma unroll 4
                        for (int i = 0; i < 64; ++i) {
                            float x0 = (rowp[2 * i]     - mean) * rinv * lng[2 * i]     + lnb[2 * i];
                            float x1 = (rowp[2 * i + 1] - mean) * rinv * lng[2 * i + 1] + lnb[2 * i + 1];
                            float fr  = exp2f((float)i * -0.2076205059304601f); // 10000^(-2i/128)
                            float ang = pv * fr;
                            float sn = __sinf(ang), cs = __cosf(ang);
                            float2 o2;
                            o2.x = x0 * cs - x1 * sn;
                            o2.y = x1 * cs + x0 * sn;
                            *(float2*)(op + 2 * i) = o2;
                        }
                    }
                }
            }
        }
    }
}

// ---------------------------------------------------------------- attention (N=32 keys), fp32 vector
__global__ __launch_bounds__(256) void attn_kernel(
    const float* __restrict__ q, const float* __restrict__ kws,
    const float* __restrict__ vws, ushort* __restrict__ obf)
{
    __shared__ float ks[NAK * HD];
    __shared__ float vs[NAK * HD];
    int tid  = threadIdx.x;
    int bh   = blockIdx.x >> 2;
    int sblk = blockIdx.x & 3;
    const float4* kg = (const float4*)(kws + (size_t)bh * NAK * HD);
    const float4* vg = (const float4*)(vws + (size_t)bh * NAK * HD);
    for (int i = tid; i < NAK * HD / 4; i += 256) {
        ((float4*)ks)[i] = kg[i];
        ((float4*)vs)[i] = vg[i];
    }
    __syncthreads();

    int s_tok = sblk * 256 + tid;
    const float* qp = q + ((size_t)bh * SEQ + s_tok) * HD;

    float sc[NAK];
    #pragma unroll
    for (int n = 0; n < NAK; ++n) sc[n] = 0.f;

    for (int dc = 0; dc < HD; dc += 32) {
        float qc[32];
        #pragma unroll
        for (int jj = 0; jj < 8; ++jj)
            *(float4*)&qc[jj * 4] = *(const float4*)(qp + dc + jj * 4);
        #pragma unroll
        for (int n = 0; n < NAK; ++n) {
            const float* kr = ks + n * HD + dc;
            float a0 = 0.f;
            #pragma unroll
            for (int jj = 0; jj < 8; ++jj) {
                float4 k4 = *(const float4*)(kr + jj * 4);
                a0 += qc[jj*4]*k4.x + qc[jj*4+1]*k4.y + qc[jj*4+2]*k4.z + qc[jj*4+3]*k4.w;
            }
            sc[n] += a0;
        }
    }
    const float scale = 0.08838834764831845f;  // 128^-0.5
    float mx = -3.4e38f;
    #pragma unroll
    for (int n = 0; n < NAK; ++n) { sc[n] *= scale; mx = fmaxf(mx, sc[n]); }
    float sum = 0.f;
    #pragma unroll
    for (int n = 0; n < NAK; ++n) { sc[n] = __expf(sc[n] - mx); sum += sc[n]; }
    float inv = 1.0f / sum;
    #pragma unroll
    for (int n = 0; n < NAK; ++n) sc[n] *= inv;

    int b = bh / NH, h = bh - b * NH;
    ushort* op = obf + ((size_t)(b * SEQ + s_tok)) * DIM + h * HD;
    for (int dc = 0; dc < HD; dc += 32) {
        float oc[32];
        #pragma unroll
        for (int j = 0; j < 32; ++j) oc[j] = 0.f;
        #pragma unroll
        for (int n = 0; n < NAK; ++n) {
            float pn = sc[n];
            const float* vr = vs + n * HD + dc;
            #pragma unroll
            for (int jj = 0; jj < 8; ++jj) {
                float4 v4 = *(const float4*)(vr + jj * 4);
                oc[jj*4]   += pn * v4.x; oc[jj*4+1] += pn * v4.y;
                oc[jj*4+2] += pn * v4.z; oc[jj*4+3] += pn * v4.w;
            }
        }
        #pragma unroll
        for (int jj = 0; jj < 8; ++jj) {
            ushort4 o4;
            o4.x = f2bf_rne(oc[jj*4]);   o4.y = f2bf_rne(oc[jj*4+1]);
            o4.z = f2bf_rne(oc[jj*4+2]); o4.w = f2bf_rne(oc[jj*4+3]);
            *(ushort4*)(op + dc + jj * 4) = o4;
        }
    }
}

// ---------------------------------------------------------------- launch
extern "C" void kernel_launch(void* const* d_in, const int* in_sizes, int n_in,
                              void* d_out, int out_size, void* d_ws, size_t ws_size,
                              hipStream_t stream) {
    const float* x    = (const float*)d_in[0];
    const float* enc  = (const float*)d_in[1];
    const float* amap = (const float*)d_in[2];
    const float* q_w  = (const float*)d_in[3];
    const float* q_b  = (const float*)d_in[4];
    const float* kv_w = (const float*)d_in[5];
    const float* kv_b = (const float*)d_in[6];
    const float* p_w  = (const float*)d_in[7];
    const float* p_b  = (const float*)d_in[8];
    const float* qn_g = (const float*)d_in[9];
    const float* qn_b = (const float*)d_in[10];
    const float* kn_g = (const float*)d_in[11];
    const float* kn_b = (const float*)d_in[12];
    float* out = (float*)d_out;

    char* ws = (char*)d_ws;
    // ws layout (bytes, 256-aligned); x_bf region is reused for attention output o_bf
    ushort* x_bf   = (ushort*)(ws);                    // 132,120,576
    ushort* qw_bf  = (ushort*)(ws + 132120576);        //  18,874,368
    ushort* pw_bf  = (ushort*)(ws + 150994944);        //  18,874,368
    ushort* enc_bf = (ushort*)(ws + 169869312);        //   1,032,192
    ushort* kvw_bf = (ushort*)(ws + 170901504);        //   9,437,184
    float*  k_ws   = (float*)(ws + 180338688);         //   8,257,536
    float*  v_ws   = (float*)(ws + 188596224);         //   8,257,536
    float*  pos    = (float*)(ws + 196853760);         //      86,016
    float*  mm     = (float*)(ws + 196939776);         //          16

    cvt_kernel<<<1024, 256, 0, stream>>>(x,    x_bf,   66060288 / 4);
    cvt_kernel<<<256,  256, 0, stream>>>(q_w,  qw_bf,  9437184 / 4);
    cvt_kernel<<<256,  256, 0, stream>>>(p_w,  pw_bf,  9437184 / 4);
    cvt_kernel<<<64,   256, 0, stream>>>(enc,  enc_bf, 516096 / 4);
    cvt_kernel<<<128,  256, 0, stream>>>(kv_w, kvw_bf, 4718592 / 4);

    minmax_kernel<<<1, 256, 0, stream>>>(amap, mm);
    pos_kernel<<<84, 256, 0, stream>>>(amap, mm, pos);

    // KV projection + k-norm + k-rope (N tiles: 24 k-heads then 24 v-heads)
    gemm_bf16_kernel<1><<<dim3(48, 6), 256, 0, stream>>>(
        enc_bf, kvw_bf, kv_b, kn_g, kn_b, nullptr, nullptr, k_ws, v_ws, MKV, ENCD);

    // Q projection + q-norm + rope -> q[b,h,s,d] parked in d_out
    gemm_bf16_kernel<0><<<dim3(24, 168), 256, 0, stream>>>(
        x_bf, qw_bf, q_b, qn_g, qn_b, pos, out, nullptr, nullptr, LTOT, DIM);

    // attention: reads q from d_out, writes o (bf16) into x_bf region
    attn_kernel<<<NT * NH * 4, 256, 0, stream>>>(out, k_ws, v_ws, x_bf);

    // output projection -> final result in d_out
    gemm_bf16_kernel<2><<<dim3(24, 168), 256, 0, stream>>>(
        x_bf, pw_bf, p_b, nullptr, nullptr, nullptr, out, nullptr, nullptr, LTOT, DIM);
}

// Round 2
// 2116.270 us; speedup vs baseline: 1.0633x; 1.0633x over previous
//
#include <hip/hip_runtime.h>
#include <hip/hip_bf16.h>

#define NT   21
#define SEQ  1024
#define DIM  3072
#define NH   24
#define HD   128
#define ENCD 768
#define NAK  32
#define LTOT (NT*SEQ)    /* 21504 */
#define MKV  (NT*NAK)    /* 672   */

typedef __bf16 bf16x8 __attribute__((ext_vector_type(8)));
typedef float  f32x4  __attribute__((ext_vector_type(4)));

__device__ __forceinline__ ushort f2bf_rne(float f) {
    unsigned int u = __float_as_uint(f);
    u += 0x7FFFu + ((u >> 16) & 1u);
    return (ushort)(u >> 16);
}
__device__ __forceinline__ float bf2f(ushort u) {
    return __uint_as_float(((unsigned int)u) << 16);
}

// ---------------------------------------------------------------- conversions
__global__ void cvt_kernel(const float* __restrict__ src, ushort* __restrict__ dst, int n4) {
    int i = blockIdx.x * blockDim.x + threadIdx.x;
    int stride = gridDim.x * blockDim.x;
    for (; i < n4; i += stride) {
        float4 v = ((const float4*)src)[i];
        ushort4 o;
        o.x = f2bf_rne(v.x); o.y = f2bf_rne(v.y);
        o.z = f2bf_rne(v.z); o.w = f2bf_rne(v.w);
        ((ushort4*)dst)[i] = o;
    }
}

// ---------------------------------------------------------------- min/max of the two attn-map rows
__global__ void minmax_kernel(const float* __restrict__ m, float* __restrict__ mm) {
    __shared__ float red[4][256];
    int tid = threadIdx.x;
    float mn0 = 3.4e38f, mx0 = -3.4e38f, mn1 = 3.4e38f, mx1 = -3.4e38f;
    for (int i = tid; i < LTOT; i += 256) {
        float a = m[i], b = m[LTOT + i];
        mn0 = fminf(mn0, a); mx0 = fmaxf(mx0, a);
        mn1 = fminf(mn1, b); mx1 = fmaxf(mx1, b);
    }
    red[0][tid] = mn0; red[1][tid] = mx0; red[2][tid] = mn1; red[3][tid] = mx1;
    __syncthreads();
    for (int s = 128; s > 0; s >>= 1) {
        if (tid < s) {
            red[0][tid] = fminf(red[0][tid], red[0][tid + s]);
            red[1][tid] = fmaxf(red[1][tid], red[1][tid + s]);
            red[2][tid] = fminf(red[2][tid], red[2][tid + s]);
            red[3][tid] = fmaxf(red[3][tid], red[3][tid + s]);
        }
        __syncthreads();
    }
    if (tid == 0) { mm[0]=red[0][0]; mm[1]=red[1][0]; mm[2]=red[2][0]; mm[3]=red[3][0]; }
}

__global__ void pos_kernel(const float* __restrict__ m, const float* __restrict__ mm,
                           float* __restrict__ pos) {
    int i = blockIdx.x * 256 + threadIdx.x;
    if (i >= LTOT) return;
    float a = m[i], b = m[LTOT + i];
    float h1 = (a - mm[0]) * (4.0f / (mm[1] - mm[0]));               // [0,4]
    float h2 = (b - mm[2]) * (4.0f / (mm[3] - mm[2])) + 20.0f;       // [20,24]
    pos[i] = (a >= b) ? h1 : h2;   // argmax over 2 rows; 'back' row is unreachable
}

// ---------------------------------------------------------------- fused bf16 GEMM (+LN+RoPE epilogues)
// BK=64: 32 MFMA per wave per barrier round (was 16) -> half the vmcnt(0) drains.
// Grid is 1D with XCD partitioning: xcd = bid&7 owns n-tiles [x*nPerXcd, (x+1)*nPerXcd),
// m-tile is the fast index -> each XCD's concurrent blocks share ONE B column-tile
// (0.75 MB, L2-resident) while all XCDs stream the same A rows (L3-resident).
// MODE 0: q = x@q_w^T + q_b -> LN(1e-6,qn) -> RoPE(pos[leff]) -> q bf16 [b,h,s,d] in d_out
// MODE 1: kv = enc@kv_w^T + kv_b; cols<3072: k -> LN(1e-5,kn) -> RoPE(2/22) -> k_ws ; else v -> v_ws
// MODE 2: out = o@proj_w^T + proj_b -> d_out row-major fp32
struct __align__(16) GemmSmem {
    union {
        ushort stage[2 * 128 * 64];  // A tile then B tile (16KB + 16KB)
        float  epi[64 * 133];        // half-tile epilogue buffer (34,048 B)
    };
};

template <int MODE>
__global__ __launch_bounds__(256, 2) void gemm_bf16_kernel(
    const ushort* __restrict__ A, const ushort* __restrict__ W,
    const float* __restrict__ bias,
    const float* __restrict__ lng, const float* __restrict__ lnb,
    const float* __restrict__ pos,
    float* __restrict__ out0, float* __restrict__ kws, float* __restrict__ vws,
    int M, int K, int nTilesM, int nPerXcd)
{
    __shared__ GemmSmem sh;
    const int tid  = threadIdx.x;
    const int lane = tid & 63;
    const int wave = tid >> 6;
    const int wm = wave >> 1, wn = wave & 1;
    const int quad = lane >> 4, r16 = lane & 15;

    // XCD-partitioned block swizzle
    const int bid = blockIdx.x;
    const int xcd = bid & 7;
    const int j   = bid >> 3;
    const int mt  = j % nTilesM;
    const int nt  = xcd * nPerXcd + j / nTilesM;
    const int m0  = mt * 128;
    const int n0  = nt * 128;

    char* smA = (char*)sh.stage;          // 128 rows x 128 B
    char* smB = smA + 16384;

    f32x4 acc[4][4] = {};

    const int nK = K >> 6;   // BK = 64
    for (int kt = 0; kt < nK; ++kt) {
        const int k0 = kt << 6;
        __syncthreads();
        // ---- stage A tile (128 x 64 bf16): 4 x 16B chunks per thread.
        // LDS slot (r, cs) holds global chunk cg = cs ^ (r&7)  (full 8-chunk XOR swizzle)
        #pragma unroll
        for (int jj = 0; jj < 4; ++jj) {
            int slot = (wave * 4 + jj) * 64 + lane;
            int r  = slot >> 3;
            int c  = (slot & 7) ^ (r & 7);
            int row = m0 + r; if (row > M - 1) row = M - 1;
            const ushort* gp = A + (size_t)row * K + (k0 + c * 8);
            __builtin_amdgcn_global_load_lds(
                (const __attribute__((address_space(1))) void*)gp,
                (__attribute__((address_space(3))) void*)(smA + (wave * 4 + jj) * 1024),
                16, 0, 0);
        }
        // ---- stage B tile (weight rows n0..n0+127)
        #pragma unroll
        for (int jj = 0; jj < 4; ++jj) {
            int slot = (wave * 4 + jj) * 64 + lane;
            int r  = slot >> 3;
            int c  = (slot & 7) ^ (r & 7);
            const ushort* gp = W + (size_t)(n0 + r) * K + (k0 + c * 8);
            __builtin_amdgcn_global_load_lds(
                (const __attribute__((address_space(1))) void*)gp,
                (__attribute__((address_space(3))) void*)(smB + (wave * 4 + jj) * 1024),
                16, 0, 0);
        }
        __syncthreads();  // vmcnt(0) drain happens here (structural)

        #pragma unroll
        for (int kk = 0; kk < 2; ++kk) {
            bf16x8 af[4], bfr[4];
            #pragma unroll
            for (int t = 0; t < 4; ++t) {
                int ra = wm * 64 + t * 16 + r16;
                af[t] = *(const bf16x8*)(smA + ra * 128 + ((((kk << 2) + quad) ^ (ra & 7)) << 4));
                int rb = wn * 64 + t * 16 + r16;
                bfr[t] = *(const bf16x8*)(smB + rb * 128 + ((((kk << 2) + quad) ^ (rb & 7)) << 4));
            }
            #pragma unroll
            for (int t = 0; t < 4; ++t)
                #pragma unroll
                for (int u = 0; u < 4; ++u)
                    acc[t][u] = __builtin_amdgcn_mfma_f32_16x16x32_bf16(af[t], bfr[u], acc[t][u], 0, 0, 0);
        }
    }

    // ---------------- epilogue: two 64-row phases through LDS
    const float inv128 = 1.0f / 128.0f;
    #pragma unroll
    for (int ph = 0; ph < 2; ++ph) {
        __syncthreads();
        if (wm == ph) {
            #pragma unroll
            for (int t = 0; t < 4; ++t)
                #pragma unroll
                for (int u = 0; u < 4; ++u)
                    #pragma unroll
                    for (int r = 0; r < 4; ++r) {
                        int ml = t * 16 + quad * 4 + r;        // 0..63 (within phase band)
                        int nl = wn * 64 + u * 16 + r16;       // 0..127
                        sh.epi[ml * 133 + nl] = acc[t][u][r];
                    }
        }
        __syncthreads();
        if (tid < 64) {
            int gm = m0 + ph * 64 + tid;
            if (gm < M) {
                float* rowp = &sh.epi[tid * 133];
                if (MODE == 2) {
                    float* op = out0 + (size_t)gm * DIM + n0;
                    #pragma unroll 8
                    for (int jj = 0; jj < 128; jj += 4) {
                        float4 b4 = *(const float4*)(bias + n0 + jj);
                        float4 v;
                        v.x = rowp[jj]     + b4.x;
                        v.y = rowp[jj + 1] + b4.y;
                        v.z = rowp[jj + 2] + b4.z;
                        v.w = rowp[jj + 3] + b4.w;
                        *(float4*)(op + jj) = v;
                    }
                } else if (MODE == 0) {
                    // q path: LN(1e-6) + RoPE, write bf16 into d_out
                    int head = n0 >> 7;
                    int b = gm >> 10, s = gm & 1023;
                    int leff = ((b * NH + head) * SEQ + s) % LTOT;   // bug-faithful flat reshape
                    float pv = pos[leff];
                    ushort* opq = (ushort*)out0 + ((size_t)(b * NH + head) * SEQ + s) * HD;
                    float s1 = 0.f, s2 = 0.f;
                    #pragma unroll 8
                    for (int jj = 0; jj < 128; ++jj) {
                        float val = rowp[jj] + bias[n0 + jj];
                        rowp[jj] = val;
                        s1 += val; s2 += val * val;
                    }
                    float mean = s1 * inv128;
                    float var  = s2 * inv128 - mean * mean;
                    float rinv = rsqrtf(var + 1e-6f);
                    #pragma unroll 4
                    for (int i = 0; i < 64; ++i) {
                        float x0 = (rowp[2 * i]     - mean) * rinv * lng[2 * i]     + lnb[2 * i];
                        float x1 = (rowp[2 * i + 1] - mean) * rinv * lng[2 * i + 1] + lnb[2 * i + 1];
                        float fr  = exp2f((float)i * -0.2076205059304601f); // 10000^(-2i/128)
                        float ang = pv * fr;
                        float sn = __sinf(ang), cs = __cosf(ang);
                        ushort2 o2;
                        o2.x = f2bf_rne(x0 * cs - x1 * sn);
                        o2.y = f2bf_rne(x1 * cs + x0 * sn);
                        *(ushort2*)(opq + 2 * i) = o2;
                    }
                } else {                // MODE 1
                    int b = gm / NAK, n = gm - b * NAK;
                    if (n0 < DIM) {     // k path: LN(1e-5) + RoPE(2/22), fp32
                        int head = n0 >> 7;
                        float pv = (n < 16) ? 2.0f : 22.0f;
                        float* op = kws + ((size_t)(b * NH + head) * NAK + n) * HD;
                        float s1 = 0.f, s2 = 0.f;
                        #pragma unroll 8
                        for (int jj = 0; jj < 128; ++jj) {
                            float val = rowp[jj] + bias[n0 + jj];
                            rowp[jj] = val;
                            s1 += val; s2 += val * val;
                        }
                        float mean = s1 * inv128;
                        float var  = s2 * inv128 - mean * mean;
                        float rinv = rsqrtf(var + 1e-5f);
                        #pragma unroll 4
                        for (int i = 0; i < 64; ++i) {
                            float x0 = (rowp[2 * i]     - mean) * rinv * lng[2 * i]     + lnb[2 * i];
                            float x1 = (rowp[2 * i + 1] - mean) * rinv * lng[2 * i + 1] + lnb[2 * i + 1];
                            float fr  = exp2f((float)i * -0.2076205059304601f);
                            float ang = pv * fr;
                            float sn = __sinf(ang), cs = __cosf(ang);
                            float2 o2;
                            o2.x = x0 * cs - x1 * sn;
                            o2.y = x1 * cs + x0 * sn;
                            *(float2*)(op + 2 * i) = o2;
                        }
                    } else {            // v path: bias only, fp32
                        int head = (n0 - DIM) >> 7;
                        float* op = vws + ((size_t)(b * NH + head) * NAK + n) * HD;
                        #pragma unroll 8
                        for (int jj = 0; jj < 128; jj += 4) {
                            float4 b4 = *(const float4*)(bias + n0 + jj);
                            float4 v;
                            v.x = rowp[jj]     + b4.x;
                            v.y = rowp[jj + 1] + b4.y;
                            v.z = rowp[jj + 2] + b4.z;
                            v.w = rowp[jj + 3] + b4.w;
                            *(float4*)(op + jj) = v;
                        }
                    }
                }
            }
        }
    }
}

// ---------------------------------------------------------------- attention (N=32 keys), fp32 vector, bf16 q
__global__ __launch_bounds__(256) void attn_kernel(
    const ushort* __restrict__ q, const float* __restrict__ kws,
    const float* __restrict__ vws, ushort* __restrict__ obf)
{
    __shared__ float ks[NAK * HD];
    __shared__ float vs[NAK * HD];
    int tid  = threadIdx.x;
    int bh   = blockIdx.x >> 2;
    int sblk = blockIdx.x & 3;
    const float4* kg = (const float4*)(kws + (size_t)bh * NAK * HD);
    const float4* vg = (const float4*)(vws + (size_t)bh * NAK * HD);
    for (int i = tid; i < NAK * HD / 4; i += 256) {
        ((float4*)ks)[i] = kg[i];
        ((float4*)vs)[i] = vg[i];
    }
    __syncthreads();

    int s_tok = sblk * 256 + tid;
    const ushort* qp = q + ((size_t)bh * SEQ + s_tok) * HD;

    float sc[NAK];
    #pragma unroll
    for (int n = 0; n < NAK; ++n) sc[n] = 0.f;

    for (int dc = 0; dc < HD; dc += 32) {
        float qc[32];
        #pragma unroll
        for (int jj = 0; jj < 8; ++jj) {
            ushort4 u4 = *(const ushort4*)(qp + dc + jj * 4);
            qc[jj*4]   = bf2f(u4.x); qc[jj*4+1] = bf2f(u4.y);
            qc[jj*4+2] = bf2f(u4.z); qc[jj*4+3] = bf2f(u4.w);
        }
        #pragma unroll
        for (int n = 0; n < NAK; ++n) {
            const float* kr = ks + n * HD + dc;
            float a0 = 0.f;
            #pragma unroll
            for (int jj = 0; jj < 8; ++jj) {
                float4 k4 = *(const float4*)(kr + jj * 4);
                a0 += qc[jj*4]*k4.x + qc[jj*4+1]*k4.y + qc[jj*4+2]*k4.z + qc[jj*4+3]*k4.w;
            }
            sc[n] += a0;
        }
    }
    const float scale = 0.08838834764831845f;  // 128^-0.5
    float mx = -3.4e38f;
    #pragma unroll
    for (int n = 0; n < NAK; ++n) { sc[n] *= scale; mx = fmaxf(mx, sc[n]); }
    float sum = 0.f;
    #pragma unroll
    for (int n = 0; n < NAK; ++n) { sc[n] = __expf(sc[n] - mx); sum += sc[n]; }
    float inv = 1.0f / sum;
    #pragma unroll
    for (int n = 0; n < NAK; ++n) sc[n] *= inv;

    int b = bh / NH, h = bh - b * NH;
    ushort* op = obf + ((size_t)(b * SEQ + s_tok)) * DIM + h * HD;
    for (int dc = 0; dc < HD; dc += 32) {
        float oc[32];
        #pragma unroll
        for (int jj = 0; jj < 32; ++jj) oc[jj] = 0.f;
        #pragma unroll
        for (int n = 0; n < NAK; ++n) {
            float pn = sc[n];
            const float* vr = vs + n * HD + dc;
            #pragma unroll
            for (int jj = 0; jj < 8; ++jj) {
                float4 v4 = *(const float4*)(vr + jj * 4);
                oc[jj*4]   += pn * v4.x; oc[jj*4+1] += pn * v4.y;
                oc[jj*4+2] += pn * v4.z; oc[jj*4+3] += pn * v4.w;
            }
        }
        #pragma unroll
        for (int jj = 0; jj < 8; ++jj) {
            ushort4 o4;
            o4.x = f2bf_rne(oc[jj*4]);   o4.y = f2bf_rne(oc[jj*4+1]);
            o4.z = f2bf_rne(oc[jj*4+2]); o4.w = f2bf_rne(oc[jj*4+3]);
            *(ushort4*)(op + dc + jj * 4) = o4;
        }
    }
}

// ---------------------------------------------------------------- launch
extern "C" void kernel_launch(void* const* d_in, const int* in_sizes, int n_in,
                              void* d_out, int out_size, void* d_ws, size_t ws_size,
                              hipStream_t stream) {
    const float* x    = (const float*)d_in[0];
    const float* enc  = (const float*)d_in[1];
    const float* amap = (const float*)d_in[2];
    const float* q_w  = (const float*)d_in[3];
    const float* q_b  = (const float*)d_in[4];
    const float* kv_w = (const float*)d_in[5];
    const float* kv_b = (const float*)d_in[6];
    const float* p_w  = (const float*)d_in[7];
    const float* p_b  = (const float*)d_in[8];
    const float* qn_g = (const float*)d_in[9];
    const float* qn_b = (const float*)d_in[10];
    const float* kn_g = (const float*)d_in[11];
    const float* kn_b = (const float*)d_in[12];
    float* out = (float*)d_out;

    char* ws = (char*)d_ws;
    // ws layout (bytes, 256-aligned); x_bf region is reused for attention output o_bf
    ushort* x_bf   = (ushort*)(ws);                    // 132,120,576
    ushort* qw_bf  = (ushort*)(ws + 132120576);        //  18,874,368
    ushort* pw_bf  = (ushort*)(ws + 150994944);        //  18,874,368
    ushort* enc_bf = (ushort*)(ws + 169869312);        //   1,032,192
    ushort* kvw_bf = (ushort*)(ws + 170901504);        //   9,437,184
    float*  k_ws   = (float*)(ws + 180338688);         //   8,257,536
    float*  v_ws   = (float*)(ws + 188596224);         //   8,257,536
    float*  pos    = (float*)(ws + 196853760);         //      86,016
    float*  mm     = (float*)(ws + 196939776);         //          16

    cvt_kernel<<<1024, 256, 0, stream>>>(x,    x_bf,   66060288 / 4);
    cvt_kernel<<<256,  256, 0, stream>>>(q_w,  qw_bf,  9437184 / 4);
    cvt_kernel<<<256,  256, 0, stream>>>(p_w,  pw_bf,  9437184 / 4);
    cvt_kernel<<<64,   256, 0, stream>>>(enc,  enc_bf, 516096 / 4);
    cvt_kernel<<<128,  256, 0, stream>>>(kv_w, kvw_bf, 4718592 / 4);

    minmax_kernel<<<1, 256, 0, stream>>>(amap, mm);
    pos_kernel<<<84, 256, 0, stream>>>(amap, mm, pos);

    // KV projection + k-norm + k-rope: 48 n-tiles x 6 m-tiles = 288 blocks (6 n-tiles/XCD)
    gemm_bf16_kernel<1><<<288, 256, 0, stream>>>(
        enc_bf, kvw_bf, kv_b, kn_g, kn_b, nullptr, nullptr, k_ws, v_ws, MKV, ENCD, 6, 6);

    // Q projection + q-norm + rope -> q bf16 [b,h,s,d] parked in d_out
    // 24 n-tiles x 168 m-tiles = 4032 blocks (3 n-tiles/XCD)
    gemm_bf16_kernel<0><<<4032, 256, 0, stream>>>(
        x_bf, qw_bf, q_b, qn_g, qn_b, pos, out, nullptr, nullptr, LTOT, DIM, 168, 3);

    // attention: reads q (bf16) from d_out, writes o (bf16) into x_bf region
    attn_kernel<<<NT * NH * 4, 256, 0, stream>>>((const ushort*)out, k_ws, v_ws, x_bf);

    // output projection -> final result in d_out (fp32)
    gemm_bf16_kernel<2><<<4032, 256, 0, stream>>>(
        x_bf, pw_bf, p_b, nullptr, nullptr, nullptr, out, nullptr, nullptr, LTOT, DIM, 168, 3);
}